// Round 4
// baseline (58.843 us; speedup 1.0000x reference)
//
#include <hip/hip_runtime.h>

// Problem constants (fixed by setup_inputs)
constexpr int B  = 32;
constexpr int M  = 512;    // entities per batch
constexpr int N  = 128;    // channels
constexpr int H  = 128;
constexpr int W  = 128;
constexpr int HW = H * W;            // 16384 = 2^14
constexpr int PLANE = N * HW;        // 2^21 elements per batch in output
constexpr size_t INV_BYTES = (size_t)B * HW * 4;   // 2 MB
constexpr size_t ZP_FLOATS = 128;                  // 512 B zero page

typedef float f4 __attribute__((ext_vector_type(4)));
typedef int   i4 __attribute__((ext_vector_type(4)));

// ---------------------------------------------------------------------------
// Kernel 1: fill inv[] with -1 (int4-vectorized) and zero the 512 B zero page.
// ---------------------------------------------------------------------------
__global__ void init_inv_kernel(int* __restrict__ inv, float* __restrict__ zpage) {
    int t = blockIdx.x * blockDim.x + threadIdx.x;   // 131072 threads
    i4 v = {-1, -1, -1, -1};
    reinterpret_cast<i4*>(inv)[t] = v;
    if (t < (int)(ZP_FLOATS / 4)) {
        f4 z = {0.f, 0.f, 0.f, 0.f};
        reinterpret_cast<f4*>(zpage)[t] = z;
    }
}

// ---------------------------------------------------------------------------
// Kernel 2: scatter entity indices into the inverse map (no overlap -> no atomics).
// ---------------------------------------------------------------------------
__global__ void build_inv_kernel(const int* __restrict__ loc, int* __restrict__ inv) {
    int tid = blockIdx.x * blockDim.x + threadIdx.x;  // B*M = 16384 threads
    int b = tid >> 9;            // / M (M=512)
    int y = loc[tid * 2 + 0];
    int x = loc[tid * 2 + 1];
    inv[b * HW + y * W + x] = tid & (M - 1);          // m
}

// ---------------------------------------------------------------------------
// Kernel 3: full output as a gather.
// Block owns PR=1024 consecutive p for one b, loops NR=32 consecutive n.
//   - inv loaded ONCE per thread (int4 for its 4 p), reused for all 32 n
//   - x rows read in contiguous 128 B runs -> each cache line fetched once
//   - invalid p -> zero page (uniform flow; reads zp[0..31] floats)
//   - stores: 1 KB coalesced per wave-instruction per plane, 32 per thread
// Grid: 32 b x 16 p-chunks x 4 n-chunks = 2048 blocks x 256 threads.
// ---------------------------------------------------------------------------
__global__ void gather_out_kernel(const float* __restrict__ x,
                                  const int* __restrict__ inv,
                                  const float* __restrict__ zpage,
                                  float* __restrict__ out) {
    int bid = blockIdx.x;
    int b  = bid >> 6;           // 64 blocks per batch
    int nc = (bid >> 4) & 3;     // n-chunk (4 of NR=32)
    int pc = bid & 15;           // p-chunk (16 of PR=1024)
    int p  = (pc << 10) + ((int)threadIdx.x << 2);   // 4 consecutive p per thread
    int n0 = nc << 5;

    const i4 iv = *reinterpret_cast<const i4*>(inv + (b << 14) + p);
    const float* xb = x + (b << 16) + n0;            // x[b, :, n0..], row stride 128

    const float* a0 = (iv[0] >= 0) ? (xb + (iv[0] << 7)) : zpage;
    const float* a1 = (iv[1] >= 0) ? (xb + (iv[1] << 7)) : zpage;
    const float* a2 = (iv[2] >= 0) ? (xb + (iv[2] << 7)) : zpage;
    const float* a3 = (iv[3] >= 0) ? (xb + (iv[3] << 7)) : zpage;

    float* ob = out + (b << 21) + (n0 << 14) + p;

    #pragma unroll
    for (int it = 0; it < 8; ++it) {                 // n = n0 + it*4 + j
        f4 x0 = *reinterpret_cast<const f4*>(a0 + (it << 2));
        f4 x1 = *reinterpret_cast<const f4*>(a1 + (it << 2));
        f4 x2 = *reinterpret_cast<const f4*>(a2 + (it << 2));
        f4 x3 = *reinterpret_cast<const f4*>(a3 + (it << 2));

        float* o = ob + (it << 16);                  // + it*4*HW
        #pragma unroll
        for (int j = 0; j < 4; ++j) {
            f4 v = {x0[j], x1[j], x2[j], x3[j]};
            *reinterpret_cast<f4*>(o + (j << 14)) = v;
        }
    }
}

// ---------------------------------------------------------------------------
extern "C" void kernel_launch(void* const* d_in, const int* in_sizes, int n_in,
                              void* d_out, int out_size, void* d_ws, size_t ws_size,
                              hipStream_t stream) {
    const float* x   = (const float*)d_in[0];
    const int*   loc = (const int*)d_in[1];
    float* out = (float*)d_out;
    int*   inv = (int*)d_ws;                           // 2 MB
    float* zpage = (float*)((char*)d_ws + INV_BYTES);  // 512 B of zeros

    init_inv_kernel<<<(B * HW / 4) / 256, 256, 0, stream>>>(inv, zpage);
    build_inv_kernel<<<(B * M) / 256, 256, 0, stream>>>(loc, inv);
    gather_out_kernel<<<2048, 256, 0, stream>>>(x, inv, zpage, out);
}

// Round 5
// 48.719 us; speedup vs baseline: 1.2078x; 1.2078x over previous
//
#include <hip/hip_runtime.h>

// Problem constants (fixed by setup_inputs)
constexpr int B  = 32;
constexpr int M  = 512;    // entities per batch
constexpr int N  = 128;    // channels
constexpr int H  = 128;
constexpr int W  = 128;
constexpr int HW = H * W;            // 16384 = 2^14
constexpr int PLANE = N * HW;        // 2^21 elements per batch

typedef float f4 __attribute__((ext_vector_type(4)));
typedef int   i4 __attribute__((ext_vector_type(4)));

// ---------------------------------------------------------------------------
// Single fused kernel.
// Grid: 32 b x 16 pc x 2 nh = 1024 blocks x 256 threads (4 blocks/CU exact).
// Each block: batch b, p-range [pc*1024, pc*1024+1024), n-half [nh*64, +64).
//
// Phase 1 (prologue): build the inverse map for this p-range in LDS.
//   - each thread reads 2 locations (one i4 from loc[b], coalesced, L2-hit)
//   - lmap[] = -1, then scatter m for locations inside the p-range
// Phase 2: gather. Thread owns p-quad = pc*1024 + tid*4; its 4 source rows
//   are fixed for all 64 n. Loads hoisted 16-at-a-time (4 n-quads x 4 rows),
//   then 16 coalesced f4 stores (1 KB/wave-instr). Invalid p -> row 0
//   (wave-broadcast, L1) + cndmask to 0.
// HBM traffic: 256 MB write + ~10 MB compulsory reads (x/loc L2/L3-resident).
// ---------------------------------------------------------------------------
__global__ __launch_bounds__(256, 4)
void fused_scatter_kernel(const float* __restrict__ x,
                          const int* __restrict__ loc,
                          float* __restrict__ out) {
    __shared__ int lmap[1024];

    const int tid = threadIdx.x;
    const int bid = blockIdx.x;
    const int b  = bid >> 5;           // 32 blocks per batch
    const int pc = (bid >> 1) & 15;    // p-chunk
    const int n0 = (bid & 1) << 6;     // n-half: 0 or 64
    const int p0 = pc << 10;

    // --- Phase 1: local inverse map ------------------------------------
    // loc[b] slice: M*2 = 1024 ints; thread reads entities 2*tid, 2*tid+1.
    const i4 lv = *reinterpret_cast<const i4*>(loc + (b << 10) + (tid << 2));

    i4 neg = {-1, -1, -1, -1};
    *reinterpret_cast<i4*>(&lmap[tid << 2]) = neg;
    __syncthreads();

    const int f0 = (lv[0] << 7) + lv[1] - p0;   // y*W + x - p0
    const int f1 = (lv[2] << 7) + lv[3] - p0;
    if ((unsigned)f0 < 1024u) lmap[f0] = (tid << 1);
    if ((unsigned)f1 < 1024u) lmap[f1] = (tid << 1) + 1;
    __syncthreads();

    // --- Phase 2: gather + stream stores --------------------------------
    const i4 iv = *reinterpret_cast<const i4*>(&lmap[tid << 2]);
    const bool v0 = iv[0] >= 0, v1 = iv[1] >= 0, v2 = iv[2] >= 0, v3 = iv[3] >= 0;

    const float* xb = x + (b << 16) + n0;       // x[b, :, n0..], row stride 128
    const float* a0 = xb + ((v0 ? iv[0] : 0) << 7);
    const float* a1 = xb + ((v1 ? iv[1] : 0) << 7);
    const float* a2 = xb + ((v2 ? iv[2] : 0) << 7);
    const float* a3 = xb + ((v3 ? iv[3] : 0) << 7);

    float* ob = out + (b << 21) + (n0 << 14) + p0 + (tid << 2);

    #pragma unroll
    for (int g = 0; g < 4; ++g) {               // 4 groups of 16 channels
        f4 xv[4][4];
        #pragma unroll
        for (int it = 0; it < 4; ++it) {        // hoisted loads: 16 f4
            const int off = (g << 4) + (it << 2);
            xv[it][0] = *reinterpret_cast<const f4*>(a0 + off);
            xv[it][1] = *reinterpret_cast<const f4*>(a1 + off);
            xv[it][2] = *reinterpret_cast<const f4*>(a2 + off);
            xv[it][3] = *reinterpret_cast<const f4*>(a3 + off);
        }
        #pragma unroll
        for (int it = 0; it < 4; ++it) {
            float* o = ob + (((g << 4) + (it << 2)) << 14);
            #pragma unroll
            for (int j = 0; j < 4; ++j) {       // n = n0 + g*16 + it*4 + j
                f4 v = {v0 ? xv[it][0][j] : 0.f,
                        v1 ? xv[it][1][j] : 0.f,
                        v2 ? xv[it][2][j] : 0.f,
                        v3 ? xv[it][3][j] : 0.f};
                *reinterpret_cast<f4*>(o + (j << 14)) = v;
            }
        }
    }
}

// ---------------------------------------------------------------------------
extern "C" void kernel_launch(void* const* d_in, const int* in_sizes, int n_in,
                              void* d_out, int out_size, void* d_ws, size_t ws_size,
                              hipStream_t stream) {
    const float* x   = (const float*)d_in[0];
    const int*   loc = (const int*)d_in[1];
    float* out = (float*)d_out;

    fused_scatter_kernel<<<1024, 256, 0, stream>>>(x, loc, out);
}